// Round 4
// baseline (487.671 us; speedup 1.0000x reference)
//
#include <hip/hip_runtime.h>
#include <math.h>

#define N 512
#define CS 384
#define CZ 128
#define CH 16
#define NH 12
#define PQ 4
#define PV 8

// workspace layout (float offsets)
#define OFF_Q     0          // 512*192
#define OFF_K     98304      // 512*192
#define OFF_QRAW  294912     // 512*144
#define OFF_KVRAW 368640     // 512*432
#define OFF_QPTS  589824     // 512*144
#define OFF_KPTS  663552     // 512*144
#define OFF_VPX   737280     // 96*512 (v_pts x-plane, row = h*8+p)
#define OFF_VPY   786432     // 96*512
#define OFF_VPZ   835584     // 96*512 -> ends 884736
#define OFF_A     884736     // 512*12*512 (A0 logits, then probs in place)
#define OFF_CAT   4030464    // 512*2112 -> 5111808
#define OFF_VT    5111808    // 192*512 (V transposed, row = h*16+c) -> 5210112
#define OFF_WBT   5210112    // 12*128 (Wb transposed [h][c]) -> 5211648

// ---------------- kernel 0: init out with bias; block 0 also writes WbT ----------------
__global__ __launch_bounds__(384) void init_out_kernel(
    const float* __restrict__ bout, const float* __restrict__ Wb,
    float* __restrict__ out, float* __restrict__ ws)
{
    out[(size_t)blockIdx.x * 384 + threadIdx.x] = bout[threadIdx.x];
    if (blockIdx.x == 0) {
        for (int idx = threadIdx.x; idx < NH * CZ; idx += 384) {
            int h = idx >> 7, c = idx & 127;
            ws[OFF_WBT + idx] = Wb[c * NH + h];   // wbT[h*128+c]
        }
    }
}

// ---------------- kernel 1: fused projections, 16-row tile, 2x4 micro ----------------
__global__ __launch_bounds__(256) void proj_kernel(
    const float* __restrict__ s,
    const float* __restrict__ Wq,  const float* __restrict__ bq,
    const float* __restrict__ Wkv, const float* __restrict__ bkv,
    const float* __restrict__ Wqp, const float* __restrict__ bqp,
    const float* __restrict__ Wkvp,const float* __restrict__ bkvp,
    float* __restrict__ ws)
{
    __shared__ float st[16 * CS];   // 24 KB
    const int n0 = blockIdx.x * 16;
    for (int idx = threadIdx.x * 4; idx < 16 * CS; idx += 1024)
        *(float4*)&st[idx] = *(const float4*)&s[n0 * CS + idx];
    __syncthreads();

    const int tc = threadIdx.x & 31;   // col quad
    const int tr = threadIdx.x >> 5;   // 0..7 row group (2 rows each)
    const int u0 = blockIdx.y * 128 + tc * 4;  // segment bounds all %4==0
    const int r0 = tr * 2;

    const float* W; const float* bptr; int ncol, lc0;
    if (u0 < 192)      { W = Wq;   bptr = bq;   ncol = 192; lc0 = u0; }
    else if (u0 < 576) { W = Wkv;  bptr = bkv;  ncol = 384; lc0 = u0 - 192; }
    else if (u0 < 720) { W = Wqp;  bptr = bqp;  ncol = 144; lc0 = u0 - 576; }
    else               { W = Wkvp; bptr = bkvp; ncol = 432; lc0 = u0 - 720; }

    float acc[2][4];
    #pragma unroll
    for (int r = 0; r < 2; r++)
        #pragma unroll
        for (int c = 0; c < 4; c++) acc[r][c] = 0.f;

    for (int k = 0; k < CS; k += 4) {
        float4 w0 = *(const float4*)&W[(k + 0) * ncol + lc0];
        float4 w1 = *(const float4*)&W[(k + 1) * ncol + lc0];
        float4 w2 = *(const float4*)&W[(k + 2) * ncol + lc0];
        float4 w3 = *(const float4*)&W[(k + 3) * ncol + lc0];
        #pragma unroll
        for (int r = 0; r < 2; r++) {
            float4 sv = *(const float4*)&st[(r0 + r) * CS + k];
            acc[r][0] += sv.x * w0.x + sv.y * w1.x + sv.z * w2.x + sv.w * w3.x;
            acc[r][1] += sv.x * w0.y + sv.y * w1.y + sv.z * w2.y + sv.w * w3.y;
            acc[r][2] += sv.x * w0.z + sv.y * w1.z + sv.z * w2.z + sv.w * w3.z;
            acc[r][3] += sv.x * w0.w + sv.y * w1.w + sv.z * w2.w + sv.w * w3.w;
        }
    }

    #pragma unroll
    for (int c = 0; c < 4; c++) {
        const int u = u0 + c;
        const float bias = bptr[lc0 + c];
        #pragma unroll
        for (int r = 0; r < 2; r++) {
            const int n = n0 + r0 + r;
            int oidx;
            if (u < 192) oidx = OFF_Q + n * 192 + u;
            else if (u < 576) {
                int lc = u - 192, h = lc >> 5, w = lc & 31;
                oidx = (w < 16) ? OFF_K + n * 192 + h * 16 + w
                                : OFF_VT + (h * 16 + (w - 16)) * 512 + n;   // V transposed
            } else if (u < 720) oidx = OFF_QRAW + n * 144 + (u - 576);
            else                oidx = OFF_KVRAW + n * 432 + (u - 720);
            ws[oidx] = acc[r][c] + bias;
        }
    }
}

// ---------------- kernel 2: rigid transform; v_pts stored as 3 [row][j] planes ----------------
__global__ __launch_bounds__(192) void point_kernel(
    const float* __restrict__ t_trans, const float* __restrict__ t_rots,
    float* __restrict__ ws)
{
    const int n = blockIdx.x;
    const int t = threadIdx.x;
    __shared__ float R[9], tr[3];
    if (t < 9) R[t] = t_rots[n * 9 + t];
    if (t < 3) tr[t] = t_trans[n * 3 + t];
    __syncthreads();

    float x0, x1, x2;
    if (t < 48) {
        int idx = t;
        x0 = ws[OFF_QRAW + n * 144 + 0 * 48 + idx];
        x1 = ws[OFF_QRAW + n * 144 + 1 * 48 + idx];
        x2 = ws[OFF_QRAW + n * 144 + 2 * 48 + idx];
        int h = idx >> 2, p = idx & 3;
        int base = OFF_QPTS + ((n * NH + h) * PQ + p) * 3;
        ws[base + 0] = R[0] * x0 + R[1] * x1 + R[2] * x2 + tr[0];
        ws[base + 1] = R[3] * x0 + R[4] * x1 + R[5] * x2 + tr[1];
        ws[base + 2] = R[6] * x0 + R[7] * x1 + R[8] * x2 + tr[2];
    } else if (t < 192) {
        int idx = t - 48;
        x0 = ws[OFF_KVRAW + n * 432 + 0 * 144 + idx];
        x1 = ws[OFF_KVRAW + n * 432 + 1 * 144 + idx];
        x2 = ws[OFF_KVRAW + n * 432 + 2 * 144 + idx];
        int h = idx / 12, p = idx % 12;
        float rx = R[0] * x0 + R[1] * x1 + R[2] * x2 + tr[0];
        float ry = R[3] * x0 + R[4] * x1 + R[5] * x2 + tr[1];
        float rz = R[6] * x0 + R[7] * x1 + R[8] * x2 + tr[2];
        if (p < PQ) {
            int base = OFF_KPTS + ((n * NH + h) * PQ + p) * 3;
            ws[base + 0] = rx; ws[base + 1] = ry; ws[base + 2] = rz;
        } else {
            int e = h * PV + (p - PQ);
            ws[OFF_VPX + e * 512 + n] = rx;
            ws[OFF_VPY + e * 512 + n] = ry;
            ws[OFF_VPZ + e * 512 + n] = rz;
        }
    }
}

// ---------------- kernel 3: A0 = cqk*qk - 0.5*hw*d2 + mask ----------------
__global__ __launch_bounds__(192) void logitA_kernel(
    const float* __restrict__ mask, const float* __restrict__ hweights,
    float* __restrict__ ws)
{
    const int j0 = blockIdx.x * 16;
    const int i0 = blockIdx.y * 16;
    const int t = threadIdx.x;

    __shared__ float qt[16 * 200];
    __shared__ float kt[16 * 200];
    __shared__ float qpt[16 * 148];
    __shared__ float kpt[16 * 148];
    __shared__ float mi[16], mj[16];

    {
        const float* src = ws + OFF_Q + i0 * 192;
        for (int idx = t * 4; idx < 3072; idx += 768)
            *(float4*)&qt[(idx / 192) * 200 + idx % 192] = *(const float4*)&src[idx];
    }
    {
        const float* src = ws + OFF_K + j0 * 192;
        for (int idx = t * 4; idx < 3072; idx += 768)
            *(float4*)&kt[(idx / 192) * 200 + idx % 192] = *(const float4*)&src[idx];
    }
    {
        const float* src = ws + OFF_QPTS + i0 * 144;
        for (int idx = t * 4; idx < 2304; idx += 768)
            *(float4*)&qpt[(idx / 144) * 148 + idx % 144] = *(const float4*)&src[idx];
    }
    {
        const float* src = ws + OFF_KPTS + j0 * 144;
        for (int idx = t * 4; idx < 2304; idx += 768)
            *(float4*)&kpt[(idx / 144) * 148 + idx % 144] = *(const float4*)&src[idx];
    }
    if (t < 16) { mi[t] = mask[i0 + t]; mj[t] = mask[j0 + t]; }
    __syncthreads();

    const int jj = t & 15;
    const int h = t >> 4;
    const float hw = log1pf(expf(hweights[h])) * 0.13608276348795434f;
    const float cqk = 0.14433756729740643f;

    float4 kr0 = *(const float4*)&kt[jj * 200 + h * 16 + 0];
    float4 kr1 = *(const float4*)&kt[jj * 200 + h * 16 + 4];
    float4 kr2 = *(const float4*)&kt[jj * 200 + h * 16 + 8];
    float4 kr3 = *(const float4*)&kt[jj * 200 + h * 16 + 12];
    float4 kp0 = *(const float4*)&kpt[jj * 148 + h * 12 + 0];
    float4 kp1 = *(const float4*)&kpt[jj * 148 + h * 12 + 4];
    float4 kp2 = *(const float4*)&kpt[jj * 148 + h * 12 + 8];
    const float mjv = mj[jj];

    for (int ii = 0; ii < 16; ii++) {
        float4 q0 = *(const float4*)&qt[ii * 200 + h * 16 + 0];
        float4 q1 = *(const float4*)&qt[ii * 200 + h * 16 + 4];
        float4 q2 = *(const float4*)&qt[ii * 200 + h * 16 + 8];
        float4 q3 = *(const float4*)&qt[ii * 200 + h * 16 + 12];
        float qk = q0.x * kr0.x + q0.y * kr0.y + q0.z * kr0.z + q0.w * kr0.w
                 + q1.x * kr1.x + q1.y * kr1.y + q1.z * kr1.z + q1.w * kr1.w
                 + q2.x * kr2.x + q2.y * kr2.y + q2.z * kr2.z + q2.w * kr2.w
                 + q3.x * kr3.x + q3.y * kr3.y + q3.z * kr3.z + q3.w * kr3.w;
        float4 p0 = *(const float4*)&qpt[ii * 148 + h * 12 + 0];
        float4 p1 = *(const float4*)&qpt[ii * 148 + h * 12 + 4];
        float4 p2 = *(const float4*)&qpt[ii * 148 + h * 12 + 8];
        float e, d2 = 0.f;
        e = p0.x - kp0.x; d2 += e * e;  e = p0.y - kp0.y; d2 += e * e;
        e = p0.z - kp0.z; d2 += e * e;  e = p0.w - kp0.w; d2 += e * e;
        e = p1.x - kp1.x; d2 += e * e;  e = p1.y - kp1.y; d2 += e * e;
        e = p1.z - kp1.z; d2 += e * e;  e = p1.w - kp1.w; d2 += e * e;
        e = p2.x - kp2.x; d2 += e * e;  e = p2.y - kp2.y; d2 += e * e;
        e = p2.z - kp2.z; d2 += e * e;  e = p2.w - kp2.w; d2 += e * e;
        float sm = 100000.0f * (mi[ii] * mjv - 1.0f);
        ws[OFF_A + ((size_t)(i0 + ii) * NH + h) * N + j0 + jj] =
            qk * cqk - 0.5f * hw * d2 + sm;
    }
}

// ---------------- kernel 4: b = z@Wb (+A0) + softmax; Wb via wave-uniform s_loads ----------------
__global__ __launch_bounds__(512) void bsoft_kernel(
    const float* __restrict__ z, const float* __restrict__ bb,
    float* ws)
{
    const int i = blockIdx.x;
    const int t = threadIdx.x;
    __shared__ float zt[128 * 132];   // 67.6 KB
    __shared__ float wred[8][4];

    const int jj = t & 127;
    const int hg = __builtin_amdgcn_readfirstlane(t >> 7);   // wave-uniform 0..3
    const int h0 = hg * 3;
    const float bb0 = bb[h0], bb1 = bb[h0 + 1], bb2 = bb[h0 + 2];
    const float cb = 0.5773502691896258f;
    const float* w0 = ws + OFF_WBT + (h0 + 0) * 128;   // uniform base -> s_load
    const float* w1 = ws + OFF_WBT + (h0 + 1) * 128;
    const float* w2 = ws + OFF_WBT + (h0 + 2) * 128;

    float lg[3][4];

    for (int T = 0; T < 4; T++) {
        __syncthreads();
        const float* zsrc = z + ((size_t)i * N + T * 128) * CZ;
        for (int idx = t * 4; idx < 16384; idx += 2048)
            *(float4*)&zt[(idx >> 7) * 132 + (idx & 127)] = *(const float4*)&zsrc[idx];
        __syncthreads();

        float a0 = bb0, a1 = bb1, a2 = bb2;
        const float* zr = &zt[jj * 132];
        #pragma unroll
        for (int c = 0; c < CZ; c += 4) {
            float4 zq = *(const float4*)&zr[c];
            float4 q0 = *(const float4*)&w0[c];
            float4 q1 = *(const float4*)&w1[c];
            float4 q2 = *(const float4*)&w2[c];
            a0 += zq.x * q0.x + zq.y * q0.y + zq.z * q0.z + zq.w * q0.w;
            a1 += zq.x * q1.x + zq.y * q1.y + zq.z * q1.z + zq.w * q1.w;
            a2 += zq.x * q2.x + zq.y * q2.y + zq.z * q2.z + zq.w * q2.w;
        }
        const float* arow = ws + OFF_A + (size_t)i * NH * N + T * 128 + jj;
        lg[0][T] = arow[(size_t)(h0 + 0) * N] + cb * a0;
        lg[1][T] = arow[(size_t)(h0 + 1) * N] + cb * a1;
        lg[2][T] = arow[(size_t)(h0 + 2) * N] + cb * a2;
    }

    const int wv = t >> 6;
    float mx[3], sm[3];
    #pragma unroll
    for (int r = 0; r < 3; r++) {
        float m = fmaxf(fmaxf(lg[r][0], lg[r][1]), fmaxf(lg[r][2], lg[r][3]));
        #pragma unroll
        for (int o = 32; o > 0; o >>= 1) m = fmaxf(m, __shfl_xor(m, o));
        mx[r] = m;
    }
    if ((t & 63) == 0) { wred[wv][0] = mx[0]; wred[wv][1] = mx[1]; wred[wv][2] = mx[2]; }
    __syncthreads();
    #pragma unroll
    for (int r = 0; r < 3; r++)
        mx[r] = fmaxf(wred[hg * 2][r], wred[hg * 2 + 1][r]);
    __syncthreads();
    #pragma unroll
    for (int r = 0; r < 3; r++) {
        float s = 0.f;
        #pragma unroll
        for (int T = 0; T < 4; T++) { lg[r][T] = __expf(lg[r][T] - mx[r]); s += lg[r][T]; }
        #pragma unroll
        for (int o = 32; o > 0; o >>= 1) s += __shfl_xor(s, o);
        sm[r] = s;
    }
    if ((t & 63) == 0) { wred[wv][0] = sm[0]; wred[wv][1] = sm[1]; wred[wv][2] = sm[2]; }
    __syncthreads();
    #pragma unroll
    for (int r = 0; r < 3; r++) {
        float inv = 1.0f / (wred[hg * 2][r] + wred[hg * 2 + 1][r]);
        float* prow = ws + OFF_A + ((size_t)i * NH + h0 + r) * N + jj;
        #pragma unroll
        for (int T = 0; T < 4; T++)
            prow[T * 128] = lg[r][T] * inv;
    }
}

// ---------------- kernel 5: o / o_pt / o_pair; probs via s_load, V/v_pts transposed ----------------
__global__ __launch_bounds__(832) void finish_kernel(
    const float* __restrict__ z, const float* __restrict__ t_trans,
    const float* __restrict__ t_rots, const float* ws_c,
    float* ws)
{
    const int i = blockIdx.x;
    const int t = threadIdx.x;
    __shared__ float red[128 * 48];   // [c][jq][h] partials, 24.6 KB

    float* cat = ws + OFF_CAT + (size_t)i * 2112;
    const float* probs = ws_c + OFF_A + (size_t)i * NH * N;

    if (t < 512) {          // o_pair partials: waves 0-7, (c, j-quarter)
        const int c = t & 127;
        const int jq = __builtin_amdgcn_readfirstlane(t >> 7);  // wave-uniform
        float op[12];
        #pragma unroll
        for (int h = 0; h < 12; h++) op[h] = 0.f;
        const float* zc = z + ((size_t)i * N + jq * 128) * CZ + c;
        const float* ab = probs + jq * 128;                     // uniform base
        for (int j0 = 0; j0 < 128; j0 += 4) {
            float zv0 = zc[(size_t)(j0 + 0) * CZ];
            float zv1 = zc[(size_t)(j0 + 1) * CZ];
            float zv2 = zc[(size_t)(j0 + 2) * CZ];
            float zv3 = zc[(size_t)(j0 + 3) * CZ];
            #pragma unroll
            for (int h = 0; h < 12; h++) {
                float4 av = *(const float4*)&ab[h * N + j0];    // s_load_dwordx4
                op[h] += av.x * zv0 + av.y * zv1 + av.z * zv2 + av.w * zv3;
            }
        }
        #pragma unroll
        for (int h = 0; h < 12; h++) red[c * 48 + jq * 12 + h] = op[h];
    } else if (t < 704) {   // o = a@v: waves 8-10, V transposed rows
        const int u = t - 512, h = u >> 4, cc = u & 15;
        const float* vt = ws_c + OFF_VT + (h * 16 + cc) * 512;
        const float* ah = probs + h * N;
        float acc = 0.f;
        for (int j = 0; j < N; j += 4) {
            float4 av = *(const float4*)&ah[j];
            float4 vv = *(const float4*)&vt[j];
            acc += av.x * vv.x + av.y * vv.y + av.z * vv.z + av.w * vv.w;
        }
        cat[h * 16 + cc] = acc;
    } else if (t < 800) {   // o_pt: plane-major v_pts
        const int u = t - 704, h = u >> 3;   // e == u
        const float* vx = ws_c + OFF_VPX + u * 512;
        const float* vy = ws_c + OFF_VPY + u * 512;
        const float* vz = ws_c + OFF_VPZ + u * 512;
        const float* ah = probs + h * N;
        float g0 = 0.f, g1 = 0.f, g2 = 0.f;
        for (int j = 0; j < N; j += 4) {
            float4 av = *(const float4*)&ah[j];
            float4 x4 = *(const float4*)&vx[j];
            float4 y4 = *(const float4*)&vy[j];
            float4 z4 = *(const float4*)&vz[j];
            g0 += av.x * x4.x + av.y * x4.y + av.z * x4.z + av.w * x4.w;
            g1 += av.x * y4.x + av.y * y4.y + av.z * y4.z + av.w * y4.w;
            g2 += av.x * z4.x + av.y * z4.y + av.z * z4.z + av.w * z4.w;
        }
        float R[9], ti[3];
        #pragma unroll
        for (int x = 0; x < 9; x++) R[x] = t_rots[i * 9 + x];
        #pragma unroll
        for (int x = 0; x < 3; x++) ti[x] = t_trans[i * 3 + x];
        g0 -= ti[0]; g1 -= ti[1]; g2 -= ti[2];
        float l0 = R[0] * g0 + R[3] * g1 + R[6] * g2;
        float l1 = R[1] * g0 + R[4] * g1 + R[7] * g2;
        float l2 = R[2] * g0 + R[5] * g1 + R[8] * g2;
        float nrm = sqrtf(l0 * l0 + l1 * l1 + l2 * l2 + 1e-8f);
        cat[192 + u] = l0;
        cat[288 + u] = l1;
        cat[384 + u] = l2;
        cat[480 + u] = nrm;
    }
    __syncthreads();
    if (t < 512) {          // reduce o_pair partials over jq
        const int c = t & 127, hg2 = t >> 7;
        #pragma unroll
        for (int r = 0; r < 3; r++) {
            int h = hg2 * 3 + r;
            float v = red[c * 48 + 0 * 12 + h] + red[c * 48 + 1 * 12 + h]
                    + red[c * 48 + 2 * 12 + h] + red[c * 48 + 3 * 12 + h];
            cat[576 + h * CZ + c] = v;
        }
    }
}

// ---------------- kernel 6: out += cat @ Wout (k-split, atomic) ----------------
__global__ __launch_bounds__(384) void out_kernel(
    const float* __restrict__ Wout, const float* __restrict__ ws,
    float* __restrict__ out)
{
    const int rt = blockIdx.x;   // 0..63: 8-row tile
    const int kc = blockIdx.y;   // 0..7:  264-k chunk
    const int t = threadIdx.x;
    __shared__ float ct[8 * 264];
    for (int idx = t * 4; idx < 8 * 264; idx += 1536) {
        int rr = idx / 264, kk = idx % 264;
        *(float4*)&ct[idx] =
            *(const float4*)&ws[OFF_CAT + (size_t)(rt * 8 + rr) * 2112 + kc * 264 + kk];
    }
    __syncthreads();
    const int cq = t % 96, rg = t / 96;   // rg 0..3, 2 rows each
    const int c0 = cq * 4;
    float acc[2][4] = {};
    const float* Wp = Wout + (size_t)kc * 264 * 384 + c0;
    for (int kk = 0; kk < 264; kk++) {
        float4 w = *(const float4*)&Wp[(size_t)kk * 384];
        float s0 = ct[(rg * 2 + 0) * 264 + kk];
        float s1 = ct[(rg * 2 + 1) * 264 + kk];
        acc[0][0] += s0 * w.x; acc[0][1] += s0 * w.y; acc[0][2] += s0 * w.z; acc[0][3] += s0 * w.w;
        acc[1][0] += s1 * w.x; acc[1][1] += s1 * w.y; acc[1][2] += s1 * w.z; acc[1][3] += s1 * w.w;
    }
    #pragma unroll
    for (int r = 0; r < 2; r++) {
        float* op = out + (size_t)(rt * 8 + rg * 2 + r) * 384 + c0;
        atomicAdd(&op[0], acc[r][0]);
        atomicAdd(&op[1], acc[r][1]);
        atomicAdd(&op[2], acc[r][2]);
        atomicAdd(&op[3], acc[r][3]);
    }
}

extern "C" void kernel_launch(void* const* d_in, const int* in_sizes, int n_in,
                              void* d_out, int out_size, void* d_ws, size_t ws_size,
                              hipStream_t stream) {
    const float* s       = (const float*)d_in[0];
    const float* z       = (const float*)d_in[1];
    const float* t_trans = (const float*)d_in[2];
    const float* t_rots  = (const float*)d_in[3];
    const float* mask    = (const float*)d_in[4];
    const float* Wq      = (const float*)d_in[5];
    const float* bq      = (const float*)d_in[6];
    const float* Wkv     = (const float*)d_in[7];
    const float* bkv     = (const float*)d_in[8];
    const float* Wqp     = (const float*)d_in[9];
    const float* bqp     = (const float*)d_in[10];
    const float* Wkvp    = (const float*)d_in[11];
    const float* bkvp    = (const float*)d_in[12];
    const float* Wb      = (const float*)d_in[13];
    const float* bb      = (const float*)d_in[14];
    const float* hweights= (const float*)d_in[15];
    const float* Wout    = (const float*)d_in[16];
    const float* bout    = (const float*)d_in[17];
    float* ws  = (float*)d_ws;
    float* out = (float*)d_out;

    init_out_kernel<<<512, 384, 0, stream>>>(bout, Wb, out, ws);
    proj_kernel<<<dim3(32, 9), 256, 0, stream>>>(s, Wq, bq, Wkv, bkv, Wqp, bqp, Wkvp, bkvp, ws);
    point_kernel<<<512, 192, 0, stream>>>(t_trans, t_rots, ws);
    logitA_kernel<<<dim3(32, 32), 192, 0, stream>>>(mask, hweights, ws);
    bsoft_kernel<<<512, 512, 0, stream>>>(z, bb, ws);
    finish_kernel<<<512, 832, 0, stream>>>(z, t_trans, t_rots, ws, ws);
    out_kernel<<<dim3(64, 8), 384, 0, stream>>>(Wout, ws, out);
}

// Round 5
// 438.537 us; speedup vs baseline: 1.1120x; 1.1120x over previous
//
#include <hip/hip_runtime.h>
#include <math.h>

#define N 512
#define CS 384
#define CZ 128
#define CH 16
#define NH 12
#define PQ 4
#define PV 8

// workspace layout (float offsets)
#define OFF_Q     0          // 512*192
#define OFF_K     98304      // 512*192
#define OFF_QRAW  294912     // 512*144
#define OFF_KVRAW 368640     // 512*432
#define OFF_QPTS  589824     // 512*144
#define OFF_KPTS  663552     // 512*144
#define OFF_VPX   737280     // 96*512 (v_pts x-plane, row = h*8+p)
#define OFF_VPY   786432     // 96*512
#define OFF_VPZ   835584     // 96*512 -> ends 884736
#define OFF_A     884736     // 512*12*512 (A0 logits, then probs in place)
#define OFF_CAT   4030464    // 512*2112 -> 5111808
#define OFF_VT    5111808    // 192*512 (V transposed, row = h*16+c) -> 5210112
#define OFF_WBT   5210112    // 12*128 (Wb transposed [h][c]) -> 5211648

// ---------------- kernel 0: init out with bias; block 0 also writes WbT ----------------
__global__ __launch_bounds__(384) void init_out_kernel(
    const float* __restrict__ bout, const float* __restrict__ Wb,
    float* __restrict__ out, float* __restrict__ ws)
{
    out[(size_t)blockIdx.x * 384 + threadIdx.x] = bout[threadIdx.x];
    if (blockIdx.x == 0) {
        for (int idx = threadIdx.x; idx < NH * CZ; idx += 384) {
            int h = idx >> 7, c = idx & 127;
            ws[OFF_WBT + idx] = Wb[c * NH + h];   // wbT[h*128+c]
        }
    }
}

// ---------------- kernel 1: fused projections, 16-row tile, 2x4 micro ----------------
__global__ __launch_bounds__(256) void proj_kernel(
    const float* __restrict__ s,
    const float* __restrict__ Wq,  const float* __restrict__ bq,
    const float* __restrict__ Wkv, const float* __restrict__ bkv,
    const float* __restrict__ Wqp, const float* __restrict__ bqp,
    const float* __restrict__ Wkvp,const float* __restrict__ bkvp,
    float* __restrict__ ws)
{
    __shared__ float st[16 * CS];   // 24 KB
    const int n0 = blockIdx.x * 16;
    for (int idx = threadIdx.x * 4; idx < 16 * CS; idx += 1024)
        *(float4*)&st[idx] = *(const float4*)&s[n0 * CS + idx];
    __syncthreads();

    const int tc = threadIdx.x & 31;   // col quad
    const int tr = threadIdx.x >> 5;   // 0..7 row group (2 rows each)
    const int u0 = blockIdx.y * 128 + tc * 4;  // segment bounds all %4==0
    const int r0 = tr * 2;

    const float* W; const float* bptr; int ncol, lc0;
    if (u0 < 192)      { W = Wq;   bptr = bq;   ncol = 192; lc0 = u0; }
    else if (u0 < 576) { W = Wkv;  bptr = bkv;  ncol = 384; lc0 = u0 - 192; }
    else if (u0 < 720) { W = Wqp;  bptr = bqp;  ncol = 144; lc0 = u0 - 576; }
    else               { W = Wkvp; bptr = bkvp; ncol = 432; lc0 = u0 - 720; }

    float acc[2][4];
    #pragma unroll
    for (int r = 0; r < 2; r++)
        #pragma unroll
        for (int c = 0; c < 4; c++) acc[r][c] = 0.f;

    for (int k = 0; k < CS; k += 4) {
        float4 w0 = *(const float4*)&W[(k + 0) * ncol + lc0];
        float4 w1 = *(const float4*)&W[(k + 1) * ncol + lc0];
        float4 w2 = *(const float4*)&W[(k + 2) * ncol + lc0];
        float4 w3 = *(const float4*)&W[(k + 3) * ncol + lc0];
        #pragma unroll
        for (int r = 0; r < 2; r++) {
            float4 sv = *(const float4*)&st[(r0 + r) * CS + k];
            acc[r][0] += sv.x * w0.x + sv.y * w1.x + sv.z * w2.x + sv.w * w3.x;
            acc[r][1] += sv.x * w0.y + sv.y * w1.y + sv.z * w2.y + sv.w * w3.y;
            acc[r][2] += sv.x * w0.z + sv.y * w1.z + sv.z * w2.z + sv.w * w3.z;
            acc[r][3] += sv.x * w0.w + sv.y * w1.w + sv.z * w2.w + sv.w * w3.w;
        }
    }

    #pragma unroll
    for (int c = 0; c < 4; c++) {
        const int u = u0 + c;
        const float bias = bptr[lc0 + c];
        #pragma unroll
        for (int r = 0; r < 2; r++) {
            const int n = n0 + r0 + r;
            int oidx;
            if (u < 192) oidx = OFF_Q + n * 192 + u;
            else if (u < 576) {
                int lc = u - 192, h = lc >> 5, w = lc & 31;
                oidx = (w < 16) ? OFF_K + n * 192 + h * 16 + w
                                : OFF_VT + (h * 16 + (w - 16)) * 512 + n;   // V transposed
            } else if (u < 720) oidx = OFF_QRAW + n * 144 + (u - 576);
            else                oidx = OFF_KVRAW + n * 432 + (u - 720);
            ws[oidx] = acc[r][c] + bias;
        }
    }
}

// ---------------- kernel 2: rigid transform; v_pts stored as 3 [row][j] planes ----------------
__global__ __launch_bounds__(192) void point_kernel(
    const float* __restrict__ t_trans, const float* __restrict__ t_rots,
    float* __restrict__ ws)
{
    const int n = blockIdx.x;
    const int t = threadIdx.x;
    __shared__ float R[9], tr[3];
    if (t < 9) R[t] = t_rots[n * 9 + t];
    if (t < 3) tr[t] = t_trans[n * 3 + t];
    __syncthreads();

    float x0, x1, x2;
    if (t < 48) {
        int idx = t;
        x0 = ws[OFF_QRAW + n * 144 + 0 * 48 + idx];
        x1 = ws[OFF_QRAW + n * 144 + 1 * 48 + idx];
        x2 = ws[OFF_QRAW + n * 144 + 2 * 48 + idx];
        int h = idx >> 2, p = idx & 3;
        int base = OFF_QPTS + ((n * NH + h) * PQ + p) * 3;
        ws[base + 0] = R[0] * x0 + R[1] * x1 + R[2] * x2 + tr[0];
        ws[base + 1] = R[3] * x0 + R[4] * x1 + R[5] * x2 + tr[1];
        ws[base + 2] = R[6] * x0 + R[7] * x1 + R[8] * x2 + tr[2];
    } else if (t < 192) {
        int idx = t - 48;
        x0 = ws[OFF_KVRAW + n * 432 + 0 * 144 + idx];
        x1 = ws[OFF_KVRAW + n * 432 + 1 * 144 + idx];
        x2 = ws[OFF_KVRAW + n * 432 + 2 * 144 + idx];
        int h = idx / 12, p = idx % 12;
        float rx = R[0] * x0 + R[1] * x1 + R[2] * x2 + tr[0];
        float ry = R[3] * x0 + R[4] * x1 + R[5] * x2 + tr[1];
        float rz = R[6] * x0 + R[7] * x1 + R[8] * x2 + tr[2];
        if (p < PQ) {
            int base = OFF_KPTS + ((n * NH + h) * PQ + p) * 3;
            ws[base + 0] = rx; ws[base + 1] = ry; ws[base + 2] = rz;
        } else {
            int e = h * PV + (p - PQ);
            ws[OFF_VPX + e * 512 + n] = rx;
            ws[OFF_VPY + e * 512 + n] = ry;
            ws[OFF_VPZ + e * 512 + n] = rz;
        }
    }
}

// ---------------- kernel 3: A0 = cqk*qk - 0.5*hw*d2 + mask ----------------
__global__ __launch_bounds__(192) void logitA_kernel(
    const float* __restrict__ mask, const float* __restrict__ hweights,
    float* __restrict__ ws)
{
    const int j0 = blockIdx.x * 16;
    const int i0 = blockIdx.y * 16;
    const int t = threadIdx.x;

    __shared__ float qt[16 * 200];
    __shared__ float kt[16 * 200];
    __shared__ float qpt[16 * 148];
    __shared__ float kpt[16 * 148];
    __shared__ float mi[16], mj[16];

    {
        const float* src = ws + OFF_Q + i0 * 192;
        for (int idx = t * 4; idx < 3072; idx += 768)
            *(float4*)&qt[(idx / 192) * 200 + idx % 192] = *(const float4*)&src[idx];
    }
    {
        const float* src = ws + OFF_K + j0 * 192;
        for (int idx = t * 4; idx < 3072; idx += 768)
            *(float4*)&kt[(idx / 192) * 200 + idx % 192] = *(const float4*)&src[idx];
    }
    {
        const float* src = ws + OFF_QPTS + i0 * 144;
        for (int idx = t * 4; idx < 2304; idx += 768)
            *(float4*)&qpt[(idx / 144) * 148 + idx % 144] = *(const float4*)&src[idx];
    }
    {
        const float* src = ws + OFF_KPTS + j0 * 144;
        for (int idx = t * 4; idx < 2304; idx += 768)
            *(float4*)&kpt[(idx / 144) * 148 + idx % 144] = *(const float4*)&src[idx];
    }
    if (t < 16) { mi[t] = mask[i0 + t]; mj[t] = mask[j0 + t]; }
    __syncthreads();

    const int jj = t & 15;
    const int h = t >> 4;
    const float hw = log1pf(expf(hweights[h])) * 0.13608276348795434f;
    const float cqk = 0.14433756729740643f;

    float4 kr0 = *(const float4*)&kt[jj * 200 + h * 16 + 0];
    float4 kr1 = *(const float4*)&kt[jj * 200 + h * 16 + 4];
    float4 kr2 = *(const float4*)&kt[jj * 200 + h * 16 + 8];
    float4 kr3 = *(const float4*)&kt[jj * 200 + h * 16 + 12];
    float4 kp0 = *(const float4*)&kpt[jj * 148 + h * 12 + 0];
    float4 kp1 = *(const float4*)&kpt[jj * 148 + h * 12 + 4];
    float4 kp2 = *(const float4*)&kpt[jj * 148 + h * 12 + 8];
    const float mjv = mj[jj];

    for (int ii = 0; ii < 16; ii++) {
        float4 q0 = *(const float4*)&qt[ii * 200 + h * 16 + 0];
        float4 q1 = *(const float4*)&qt[ii * 200 + h * 16 + 4];
        float4 q2 = *(const float4*)&qt[ii * 200 + h * 16 + 8];
        float4 q3 = *(const float4*)&qt[ii * 200 + h * 16 + 12];
        float qk = q0.x * kr0.x + q0.y * kr0.y + q0.z * kr0.z + q0.w * kr0.w
                 + q1.x * kr1.x + q1.y * kr1.y + q1.z * kr1.z + q1.w * kr1.w
                 + q2.x * kr2.x + q2.y * kr2.y + q2.z * kr2.z + q2.w * kr2.w
                 + q3.x * kr3.x + q3.y * kr3.y + q3.z * kr3.z + q3.w * kr3.w;
        float4 p0 = *(const float4*)&qpt[ii * 148 + h * 12 + 0];
        float4 p1 = *(const float4*)&qpt[ii * 148 + h * 12 + 4];
        float4 p2 = *(const float4*)&qpt[ii * 148 + h * 12 + 8];
        float e, d2 = 0.f;
        e = p0.x - kp0.x; d2 += e * e;  e = p0.y - kp0.y; d2 += e * e;
        e = p0.z - kp0.z; d2 += e * e;  e = p0.w - kp0.w; d2 += e * e;
        e = p1.x - kp1.x; d2 += e * e;  e = p1.y - kp1.y; d2 += e * e;
        e = p1.z - kp1.z; d2 += e * e;  e = p1.w - kp1.w; d2 += e * e;
        e = p2.x - kp2.x; d2 += e * e;  e = p2.y - kp2.y; d2 += e * e;
        e = p2.z - kp2.z; d2 += e * e;  e = p2.w - kp2.w; d2 += e * e;
        float sm = 100000.0f * (mi[ii] * mjv - 1.0f);
        ws[OFF_A + ((size_t)(i0 + ii) * NH + h) * N + j0 + jj] =
            qk * cqk - 0.5f * hw * d2 + sm;
    }
}

// ---------------- kernel 4: b = z@Wb (+A0) + softmax ----------------
__global__ __launch_bounds__(512) void bsoft_kernel(
    const float* __restrict__ z, const float* __restrict__ bb,
    float* ws)
{
    const int i = blockIdx.x;
    const int t = threadIdx.x;
    __shared__ float zt[128 * 132];   // 67.6 KB
    __shared__ float wred[8][4];

    const int jj = t & 127;
    const int hg = __builtin_amdgcn_readfirstlane(t >> 7);   // wave-uniform 0..3
    const int h0 = hg * 3;
    const float bb0 = bb[h0], bb1 = bb[h0 + 1], bb2 = bb[h0 + 2];
    const float cb = 0.5773502691896258f;
    const float* w0 = ws + OFF_WBT + (h0 + 0) * 128;
    const float* w1 = ws + OFF_WBT + (h0 + 1) * 128;
    const float* w2 = ws + OFF_WBT + (h0 + 2) * 128;

    float lg[3][4];

    for (int T = 0; T < 4; T++) {
        __syncthreads();
        const float* zsrc = z + ((size_t)i * N + T * 128) * CZ;
        for (int idx = t * 4; idx < 16384; idx += 2048)
            *(float4*)&zt[(idx >> 7) * 132 + (idx & 127)] = *(const float4*)&zsrc[idx];
        __syncthreads();

        float a0 = bb0, a1 = bb1, a2 = bb2;
        const float* zr = &zt[jj * 132];
        #pragma unroll
        for (int c = 0; c < CZ; c += 4) {
            float4 zq = *(const float4*)&zr[c];
            float4 q0 = *(const float4*)&w0[c];
            float4 q1 = *(const float4*)&w1[c];
            float4 q2 = *(const float4*)&w2[c];
            a0 += zq.x * q0.x + zq.y * q0.y + zq.z * q0.z + zq.w * q0.w;
            a1 += zq.x * q1.x + zq.y * q1.y + zq.z * q1.z + zq.w * q1.w;
            a2 += zq.x * q2.x + zq.y * q2.y + zq.z * q2.z + zq.w * q2.w;
        }
        const float* arow = ws + OFF_A + (size_t)i * NH * N + T * 128 + jj;
        lg[0][T] = arow[(size_t)(h0 + 0) * N] + cb * a0;
        lg[1][T] = arow[(size_t)(h0 + 1) * N] + cb * a1;
        lg[2][T] = arow[(size_t)(h0 + 2) * N] + cb * a2;
    }

    const int wv = t >> 6;
    float mx[3], sm[3];
    #pragma unroll
    for (int r = 0; r < 3; r++) {
        float m = fmaxf(fmaxf(lg[r][0], lg[r][1]), fmaxf(lg[r][2], lg[r][3]));
        #pragma unroll
        for (int o = 32; o > 0; o >>= 1) m = fmaxf(m, __shfl_xor(m, o));
        mx[r] = m;
    }
    if ((t & 63) == 0) { wred[wv][0] = mx[0]; wred[wv][1] = mx[1]; wred[wv][2] = mx[2]; }
    __syncthreads();
    #pragma unroll
    for (int r = 0; r < 3; r++)
        mx[r] = fmaxf(wred[hg * 2][r], wred[hg * 2 + 1][r]);
    __syncthreads();
    #pragma unroll
    for (int r = 0; r < 3; r++) {
        float s = 0.f;
        #pragma unroll
        for (int T = 0; T < 4; T++) { lg[r][T] = __expf(lg[r][T] - mx[r]); s += lg[r][T]; }
        #pragma unroll
        for (int o = 32; o > 0; o >>= 1) s += __shfl_xor(s, o);
        sm[r] = s;
    }
    if ((t & 63) == 0) { wred[wv][0] = sm[0]; wred[wv][1] = sm[1]; wred[wv][2] = sm[2]; }
    __syncthreads();
    #pragma unroll
    for (int r = 0; r < 3; r++) {
        float inv = 1.0f / (wred[hg * 2][r] + wred[hg * 2 + 1][r]);
        float* prow = ws + OFF_A + ((size_t)i * NH + h0 + r) * N + jj;
        #pragma unroll
        for (int T = 0; T < 4; T++)
            prow[T * 128] = lg[r][T] * inv;
    }
}

// ---------------- kernel 5: o / o_pt / o_pair; probs staged in LDS, b128 broadcasts ----------------
// 576 threads = 9 waves. Waves 0-3: o_pair partials (wave = j-quarter, lane covers c=2l,2l+1).
// Waves 4-6: o (192 thr). Waves 7-8: o_pt (96 thr). Then cross-wave o_pair reduce.
__global__ __launch_bounds__(576) void finish_kernel(
    const float* __restrict__ z, const float* __restrict__ t_trans,
    const float* __restrict__ t_rots, const float* __restrict__ ws_c,
    float* __restrict__ ws)
{
    const int i = blockIdx.x;
    const int t = threadIdx.x;
    __shared__ float a_s[12 * 520];    // probs, 24.96 KB
    __shared__ float red[48 * 128];    // o_pair partials [w*12+h][c], 24.58 KB

    {   // stage probs (coalesced float4)
        const float* src = ws_c + OFF_A + (size_t)i * (NH * N);
        for (int idx = t * 4; idx < NH * N; idx += 576 * 4) {
            float4 v = *(const float4*)&src[idx];
            *(float4*)&a_s[(idx >> 9) * 520 + (idx & 511)] = v;
        }
    }
    __syncthreads();

    float* cat = ws + OFF_CAT + (size_t)i * 2112;
    const int wave = t >> 6;
    const int lane = t & 63;

    if (wave < 4) {         // o_pair partials: j in [wave*128, +128), c = 2*lane, 2*lane+1
        const int c0 = 2 * lane;
        float acc[12][2];
        #pragma unroll
        for (int h = 0; h < 12; h++) { acc[h][0] = 0.f; acc[h][1] = 0.f; }
        const float* zbase = z + ((size_t)i * N + wave * 128) * CZ + c0;
        const int jb = wave * 128;
        for (int j0 = 0; j0 < 128; j0 += 4) {
            float2 z0 = *(const float2*)&zbase[(size_t)(j0 + 0) * CZ];
            float2 z1 = *(const float2*)&zbase[(size_t)(j0 + 1) * CZ];
            float2 z2 = *(const float2*)&zbase[(size_t)(j0 + 2) * CZ];
            float2 z3 = *(const float2*)&zbase[(size_t)(j0 + 3) * CZ];
            #pragma unroll
            for (int h = 0; h < 12; h++) {
                float4 p = *(const float4*)&a_s[h * 520 + jb + j0];  // wave-uniform broadcast
                acc[h][0] += p.x * z0.x + p.y * z1.x + p.z * z2.x + p.w * z3.x;
                acc[h][1] += p.x * z0.y + p.y * z1.y + p.z * z2.y + p.w * z3.y;
            }
        }
        #pragma unroll
        for (int h = 0; h < 12; h++)
            *(float2*)&red[(wave * 12 + h) * 128 + c0] = make_float2(acc[h][0], acc[h][1]);
    } else if (wave < 7) {  // o = a@v: 192 threads, VT rows contiguous in j
        const int u = t - 256, h = u >> 4, cc = u & 15;
        const float* vt = ws_c + OFF_VT + (h * 16 + cc) * 512;
        const float* ah = a_s + h * 520;
        float acc = 0.f;
        for (int j = 0; j < N; j += 4) {
            float4 av = *(const float4*)&ah[j];
            float4 vv = *(const float4*)&vt[j];
            acc += av.x * vv.x + av.y * vv.y + av.z * vv.z + av.w * vv.w;
        }
        cat[h * 16 + cc] = acc;
    } else if (t < 544) {   // o_pt: 96 threads, plane-major v_pts
        const int u = t - 448, h = u >> 3;
        const float* vx = ws_c + OFF_VPX + u * 512;
        const float* vy = ws_c + OFF_VPY + u * 512;
        const float* vz = ws_c + OFF_VPZ + u * 512;
        const float* ah = a_s + h * 520;
        float g0 = 0.f, g1 = 0.f, g2 = 0.f;
        for (int j = 0; j < N; j += 4) {
            float4 av = *(const float4*)&ah[j];
            float4 x4 = *(const float4*)&vx[j];
            float4 y4 = *(const float4*)&vy[j];
            float4 z4 = *(const float4*)&vz[j];
            g0 += av.x * x4.x + av.y * x4.y + av.z * x4.z + av.w * x4.w;
            g1 += av.x * y4.x + av.y * y4.y + av.z * y4.z + av.w * y4.w;
            g2 += av.x * z4.x + av.y * z4.y + av.z * z4.z + av.w * z4.w;
        }
        float R[9], ti[3];
        #pragma unroll
        for (int x = 0; x < 9; x++) R[x] = t_rots[i * 9 + x];
        #pragma unroll
        for (int x = 0; x < 3; x++) ti[x] = t_trans[i * 3 + x];
        g0 -= ti[0]; g1 -= ti[1]; g2 -= ti[2];
        float l0 = R[0] * g0 + R[3] * g1 + R[6] * g2;
        float l1 = R[1] * g0 + R[4] * g1 + R[7] * g2;
        float l2 = R[2] * g0 + R[5] * g1 + R[8] * g2;
        float nrm = sqrtf(l0 * l0 + l1 * l1 + l2 * l2 + 1e-8f);
        cat[192 + u] = l0;
        cat[288 + u] = l1;
        cat[384 + u] = l2;
        cat[480 + u] = nrm;
    }
    __syncthreads();
    if (t < 512) {          // reduce o_pair partials over the 4 j-quarters
        const int c = t & 127, hg = t >> 7;
        #pragma unroll
        for (int r = 0; r < 3; r++) {
            int h = hg * 3 + r;
            float v = red[(0 * 12 + h) * 128 + c] + red[(1 * 12 + h) * 128 + c]
                    + red[(2 * 12 + h) * 128 + c] + red[(3 * 12 + h) * 128 + c];
            cat[576 + h * CZ + c] = v;
        }
    }
}

// ---------------- kernel 6: out += cat @ Wout (k-split, atomic) ----------------
__global__ __launch_bounds__(384) void out_kernel(
    const float* __restrict__ Wout, const float* __restrict__ ws,
    float* __restrict__ out)
{
    const int rt = blockIdx.x;   // 0..63: 8-row tile
    const int kc = blockIdx.y;   // 0..7:  264-k chunk
    const int t = threadIdx.x;
    __shared__ float ct[8 * 264];
    for (int idx = t * 4; idx < 8 * 264; idx += 1536) {
        int rr = idx / 264, kk = idx % 264;
        *(float4*)&ct[idx] =
            *(const float4*)&ws[OFF_CAT + (size_t)(rt * 8 + rr) * 2112 + kc * 264 + kk];
    }
    __syncthreads();
    const int cq = t % 96, rg = t / 96;
    const int c0 = cq * 4;
    float acc[2][4] = {};
    const float* Wp = Wout + (size_t)kc * 264 * 384 + c0;
    for (int kk = 0; kk < 264; kk++) {
        float4 w = *(const float4*)&Wp[(size_t)kk * 384];
        float s0 = ct[(rg * 2 + 0) * 264 + kk];
        float s1 = ct[(rg * 2 + 1) * 264 + kk];
        acc[0][0] += s0 * w.x; acc[0][1] += s0 * w.y; acc[0][2] += s0 * w.z; acc[0][3] += s0 * w.w;
        acc[1][0] += s1 * w.x; acc[1][1] += s1 * w.y; acc[1][2] += s1 * w.z; acc[1][3] += s1 * w.w;
    }
    #pragma unroll
    for (int r = 0; r < 2; r++) {
        float* op = out + (size_t)(rt * 8 + rg * 2 + r) * 384 + c0;
        atomicAdd(&op[0], acc[r][0]);
        atomicAdd(&op[1], acc[r][1]);
        atomicAdd(&op[2], acc[r][2]);
        atomicAdd(&op[3], acc[r][3]);
    }
}

extern "C" void kernel_launch(void* const* d_in, const int* in_sizes, int n_in,
                              void* d_out, int out_size, void* d_ws, size_t ws_size,
                              hipStream_t stream) {
    const float* s       = (const float*)d_in[0];
    const float* z       = (const float*)d_in[1];
    const float* t_trans = (const float*)d_in[2];
    const float* t_rots  = (const float*)d_in[3];
    const float* mask    = (const float*)d_in[4];
    const float* Wq      = (const float*)d_in[5];
    const float* bq      = (const float*)d_in[6];
    const float* Wkv     = (const float*)d_in[7];
    const float* bkv     = (const float*)d_in[8];
    const float* Wqp     = (const float*)d_in[9];
    const float* bqp     = (const float*)d_in[10];
    const float* Wkvp    = (const float*)d_in[11];
    const float* bkvp    = (const float*)d_in[12];
    const float* Wb      = (const float*)d_in[13];
    const float* bb      = (const float*)d_in[14];
    const float* hweights= (const float*)d_in[15];
    const float* Wout    = (const float*)d_in[16];
    const float* bout    = (const float*)d_in[17];
    float* ws  = (float*)d_ws;
    float* out = (float*)d_out;

    init_out_kernel<<<512, 384, 0, stream>>>(bout, Wb, out, ws);
    proj_kernel<<<dim3(32, 9), 256, 0, stream>>>(s, Wq, bq, Wkv, bkv, Wqp, bqp, Wkvp, bkvp, ws);
    point_kernel<<<512, 192, 0, stream>>>(t_trans, t_rots, ws);
    logitA_kernel<<<dim3(32, 32), 192, 0, stream>>>(mask, hweights, ws);
    bsoft_kernel<<<512, 512, 0, stream>>>(z, bb, ws);
    finish_kernel<<<512, 576, 0, stream>>>(z, t_trans, t_rots, ws, ws);
    out_kernel<<<dim3(64, 8), 384, 0, stream>>>(Wout, ws, out);
}